// Round 11
// baseline (86.167 us; speedup 1.0000x reference)
//
#include <hip/hip_runtime.h>

#define SIZE 128
#define TPB 4   // tiles (64 rows) per block: 4096/4 = 1024 blocks

typedef short short8 __attribute__((ext_vector_type(8)));
typedef float f32x4 __attribute__((ext_vector_type(4)));

__device__ __forceinline__ unsigned short f2bf(float f) {
    unsigned int u = __float_as_uint(f);
    unsigned int r = u + 0x7FFFu + ((u >> 16) & 1u);
    return (unsigned short)(r >> 16);
}

// gr = Re(ifft(b)). DyT affine folded into the conv matrix:
//   Gt[c][k] = w[k] * gr[(c-k)&127]   (bf16, 32 KB)
//   C0[c]    = sum_k bias[k] * gr[(c-k)&127]   (f32, 512 B)
__global__ void build_gt(const float* __restrict__ br, const float* __restrict__ bi,
                         const float* __restrict__ w, const float* __restrict__ bias,
                         unsigned short* __restrict__ Gt, float* __restrict__ C0) {
    __shared__ float gr[SIZE];
    const int t = threadIdx.x;  // 0..127
    float acc = 0.0f;
    for (int j = 0; j < SIZE; ++j) {
        int p = (j * t) & 127;
        float a = (float)p * (1.0f / 64.0f);   // angle in units of pi
        acc += br[j] * cospif(a) - bi[j] * sinpif(a);
    }
    gr[t] = acc * (1.0f / 128.0f);
    __syncthreads();
    float c0 = 0.0f;
    for (int k = 0; k < SIZE; ++k) {
        const float g = gr[(t - k) & 127];
        c0 += bias[k] * g;
        Gt[t * SIZE + k] = f2bf(w[k] * g);
    }
    C0[t] = c0;
}

// async 16B global->LDS (linear LDS dest: base + lane*16)
__device__ __forceinline__ void cp16_g2l(const float* g, float* l) {
    __builtin_amdgcn_global_load_lds(
        (const __attribute__((address_space(1))) unsigned int*)g,
        (__attribute__((address_space(3))) unsigned int*)l, 16, 0, 0);
}

// out[r][c] = sum_k tanh(alpha*x[r][k]) * Gt[c][k] + C0[c] + x[r][c]
// Pipeline: tile t+1's x streams into LDS buf^1 via global_load_lds (async,
// zero VGPR) while tile t computes from buf. Raw s_barrier + counted vmcnt(8)
// keep the prefetch in flight across barriers (__syncthreads would drain it).
// x lives ONLY in LDS: tanh reads it in A-fragment order, residual in
// D-fragment order. 16B-chunk XOR swizzle (chunk ^= row&7) applied on the
// GLOBAL source (LDS dest stays linear per gload_lds rules) and on every
// LDS read -> bank-balanced. Direct fragment stores (clean 131 MB, cf. R3).
__global__ __launch_bounds__(256, 2) void fourier_main(
    const float* __restrict__ x, const float* __restrict__ alpha_p,
    const unsigned short* __restrict__ Gt, const float* __restrict__ C0,
    float* __restrict__ out) {
    __shared__ float xs[2][64 * SIZE];  // 2 x 32 KB double buffer

    const int tid = threadIdx.x;
    const int lane = tid & 63;
    const int wv = tid >> 6;
    const int lrow = lane & 15;   // fragment row selector
    const int slot = lane >> 4;   // fragment k-chunk / col-group selector
    const int colb = wv * 32;     // this wave's output column band

    const float a2 = 2.0f * alpha_p[0];
    const unsigned blockBase = (unsigned)blockIdx.x * (TPB * 64u * SIZE);

    // ---- G fragments (8 KB/wave, L2-resident) + C0 for this wave's cols ----
    short8 gf[2][4];
    float4 c0v[2];
#pragma unroll
    for (int nt = 0; nt < 2; ++nt) {
        const int c = colb + nt * 16 + lrow;
#pragma unroll
        for (int kt = 0; kt < 4; ++kt)
            gf[nt][kt] = *reinterpret_cast<const short8*>(
                &Gt[c * SIZE + kt * 32 + slot * 8]);
        c0v[nt] = *reinterpret_cast<const float4*>(&C0[colb + nt * 16 + slot * 4]);
    }

    // ---- async stage of one 64x128 tile: wave wv covers rows 16wv..16wv+15 ----
    // lane l of issue i lands at LDS row 16wv+2i+(l>>5), chunk l&31 (linear).
    // global source pre-swizzled: chunk c' holds x chunk c'^(row&7).
    const int rh = lane >> 5;
    const int cc = lane & 31;
    auto stage = [&](int t, int buf) __attribute__((always_inline)) {
        const float* src = x + blockBase + (unsigned)t * (64u * SIZE);
#pragma unroll
        for (int i = 0; i < 8; ++i) {
            const int r = 16 * wv + 2 * i + rh;
            const float* g = src + (unsigned)r * SIZE + (unsigned)((cc ^ (r & 7)) << 2);
            float* l = &xs[buf][(16 * wv + 2 * i) * SIZE];  // wave-uniform base
            cp16_g2l(g, l);
        }
    };

    stage(0, 0);  // prologue: tile 0 in flight

#pragma unroll
    for (int t = 0; t < TPB; ++t) {
        // B_pre: everyone done READING buf[(t+1)&1] (tile t-1's compute)
        __builtin_amdgcn_s_barrier();
        if (t + 1 < TPB) stage(t + 1, (t + 1) & 1);

        // wait own tile-t loads (8 newest outstanding = tile t+1's prefetch)
        if (t + 1 < TPB) {
            asm volatile("s_waitcnt vmcnt(8)" ::: "memory");
        } else {
            asm volatile("s_waitcnt vmcnt(0)" ::: "memory");
        }
        __builtin_amdgcn_sched_barrier(0);
        __builtin_amdgcn_s_barrier();  // B_post: all waves' tile-t rows visible
        __builtin_amdgcn_sched_barrier(0);

        // ---- compute tile t from xs[t&1] ----
        const float* xb = &xs[t & 1][0];
        const unsigned tbase = blockBase + (unsigned)t * (64u * SIZE);
#pragma unroll
        for (int mt = 0; mt < 4; ++mt) {
            const int r = mt * 16 + lrow;
            const unsigned rb = (unsigned)r * SIZE;
            const int sw = r & 7;

            // x[r][k], k = kt*32+slot*8..+7  (A-fragment order), swizzled chunks
            f32x4 xk[8];
#pragma unroll
            for (int kt = 0; kt < 4; ++kt)
#pragma unroll
                for (int j = 0; j < 2; ++j) {
                    const int chunk = kt * 8 + slot * 2 + j;
                    xk[kt * 2 + j] = *reinterpret_cast<const f32x4*>(
                        &xb[rb + (unsigned)((chunk ^ sw) << 2)]);
                }

            // h = tanh(alpha*x) -> bf16 fragments;  tanh(t) = 1 - 2/(1+e^{2t})
            short8 hf[4];
#pragma unroll
            for (int kt = 0; kt < 4; ++kt) {
                short8 h;
#pragma unroll
                for (int j = 0; j < 2; ++j) {
                    const f32x4 v = xk[kt * 2 + j];
#pragma unroll
                    for (int e = 0; e < 4; ++e) {
                        const float ex = __expf(a2 * v[e]);
                        const float th =
                            fmaf(-2.0f, __builtin_amdgcn_rcpf(1.0f + ex), 1.0f);
                        h[j * 4 + e] = (short)f2bf(th);
                    }
                }
                hf[kt] = h;
            }

#pragma unroll
            for (int nt = 0; nt < 2; ++nt) {
                f32x4 a = {0.f, 0.f, 0.f, 0.f};
#pragma unroll
                for (int kt = 0; kt < 4; ++kt)
                    a = __builtin_amdgcn_mfma_f32_16x16x32_bf16(gf[nt][kt], hf[kt],
                                                                a, 0, 0, 0);
                // D: row r, cols = colb + nt*16 + slot*4 + reg
                const int chunk_r = (colb >> 2) + nt * 4 + slot;
                const f32x4 xa = *reinterpret_cast<const f32x4*>(
                    &xb[rb + (unsigned)((chunk_r ^ sw) << 2)]);
                float4 o;
                o.x = a[0] + c0v[nt].x + xa[0];
                o.y = a[1] + c0v[nt].y + xa[1];
                o.z = a[2] + c0v[nt].z + xa[2];
                o.w = a[3] + c0v[nt].w + xa[3];
                *reinterpret_cast<float4*>(
                    &out[tbase + rb + (unsigned)(chunk_r << 2)]) = o;
            }
        }
    }
}

extern "C" void kernel_launch(void* const* d_in, const int* in_sizes, int n_in,
                              void* d_out, int out_size, void* d_ws, size_t ws_size,
                              hipStream_t stream) {
    const float* x = (const float*)d_in[0];
    const float* alpha = (const float*)d_in[1];
    const float* dyt_w = (const float*)d_in[2];
    const float* dyt_b = (const float*)d_in[3];
    // d_in[4] = a_real, d_in[5] = a_imag, d_in[8] = ffn_bias: dead code in reference
    const float* b_real = (const float*)d_in[6];
    const float* b_imag = (const float*)d_in[7];
    float* out = (float*)d_out;

    unsigned short* Gt = (unsigned short*)d_ws;            // 32 KB bf16
    float* C0 = (float*)((char*)d_ws + SIZE * SIZE * 2);   // 512 B f32

    build_gt<<<1, 128, 0, stream>>>(b_real, b_imag, dyt_w, dyt_b, Gt, C0);

    const int rows = out_size / SIZE;        // 262144
    const int nblocks = rows / (64 * TPB);   // 1024
    fourier_main<<<nblocks, 256, 0, stream>>>(x, alpha, Gt, C0, out);
}

// Round 12
// 76.876 us; speedup vs baseline: 1.1209x; 1.1209x over previous
//
#include <hip/hip_runtime.h>

#define SIZE 128
#define ROWS 32     // rows per tile
#define TPB 8       // tiles per block: 262144/32/8 = 1024 blocks = 4/CU exact
#define PITCH 136   // hA row pitch in bf16 (136*2B = 272B; 272%128 != 0 -> spread)

typedef short short8 __attribute__((ext_vector_type(8)));
typedef float f32x4 __attribute__((ext_vector_type(4)));

__device__ __forceinline__ unsigned short f2bf(float f) {
    unsigned int u = __float_as_uint(f);
    unsigned int r = u + 0x7FFFu + ((u >> 16) & 1u);
    return (unsigned short)(r >> 16);
}

// gr = Re(ifft(b)). DyT affine folded into the conv matrix:
//   Gt[c][k] = w[k] * gr[(c-k)&127]   (bf16, 32 KB)
//   C0[c]    = sum_k bias[k] * gr[(c-k)&127]   (f32, 512 B)
__global__ void build_gt(const float* __restrict__ br, const float* __restrict__ bi,
                         const float* __restrict__ w, const float* __restrict__ bias,
                         unsigned short* __restrict__ Gt, float* __restrict__ C0) {
    __shared__ float gr[SIZE];
    const int t = threadIdx.x;  // 0..127
    float acc = 0.0f;
    for (int j = 0; j < SIZE; ++j) {
        int p = (j * t) & 127;
        float a = (float)p * (1.0f / 64.0f);   // angle in units of pi
        acc += br[j] * cospif(a) - bi[j] * sinpif(a);
    }
    gr[t] = acc * (1.0f / 128.0f);
    __syncthreads();
    float c0 = 0.0f;
    for (int k = 0; k < SIZE; ++k) {
        const float g = gr[(t - k) & 127];
        c0 += bias[k] * g;
        Gt[t * SIZE + k] = f2bf(w[k] * g);
    }
    C0[t] = c0;
}

// out[r][c] = sum_k tanh(alpha*x[r][k]) * Gt[c][k] + C0[c] + x[r][c]
// Multi-tile async pipeline, defects of R11 fixed:
//  - tanh ONCE per element (linear staging order), not 4x in fragment order
//  - static padded LDS addressing (no swizzle VALU); hA only in LDS (17.4 KB)
//  - residual re-read from global in fragment order (L3-absorbed, cf. R3)
//  - one raw s_barrier + lgkmcnt(0) per tile; vmcnt NEVER drained -> tile-t
//    stores and tile-(t+1) loads stay in flight across barriers
//  - 1024 blocks = 4/CU exact, 16 waves/CU, VGPR ~100 (cap 128, no spill)
__global__ __launch_bounds__(256, 4) void fourier_main(
    const float* __restrict__ x, const float* __restrict__ alpha_p,
    const unsigned short* __restrict__ Gt, const float* __restrict__ C0,
    float* __restrict__ out) {
    __shared__ unsigned short hA[2][ROWS * PITCH];  // 2 x 8.7 KB bf16 h tiles

    const int tid = threadIdx.x;
    const int lane = tid & 63;
    const int wv = tid >> 6;
    const int lrow = lane & 15;   // fragment row selector
    const int slot = lane >> 4;   // fragment k-chunk / col-group selector
    const int colb = wv * 32;     // this wave's output column band

    // tanh(t) = 1 - 2/(1+2^(t*2*log2e)); fold 2*alpha*log2e into one constant
    const float a2l = 2.0f * 1.44269504f * alpha_p[0];

    // ---- G fragments (8 KB/wave, L2-resident) + C0 for this wave's cols ----
    short8 gf[2][4];
    float4 c0v[2];
#pragma unroll
    for (int nt = 0; nt < 2; ++nt) {
        const int c = colb + nt * 16 + lrow;
#pragma unroll
        for (int kt = 0; kt < 4; ++kt)
            gf[nt][kt] = *reinterpret_cast<const short8*>(
                &Gt[c * SIZE + kt * 32 + slot * 8]);
        c0v[nt] = *reinterpret_cast<const float4*>(&C0[colb + nt * 16 + slot * 4]);
    }

    const unsigned blockBase = (unsigned)blockIdx.x * (TPB * ROWS * SIZE);
    const int srow = tid >> 5;       // staging: row = i*8 + srow
    const int scol = (tid & 31) * 4; //          col = scol

    // contiguous linear loads: 4 x 1KB/wave-instr per tile
    auto stage = [&](int t, float4 (&xn)[4]) __attribute__((always_inline)) {
        const float* src = x + blockBase + (unsigned)t * (ROWS * SIZE);
#pragma unroll
        for (int i = 0; i < 4; ++i)
            xn[i] = *reinterpret_cast<const float4*>(&src[i * 1024 + tid * 4]);
    };
    // tanh once, linear order -> bf16 -> hA[buf]
    auto hwrite = [&](int buf, const float4 (&xn)[4]) __attribute__((always_inline)) {
#pragma unroll
        for (int i = 0; i < 4; ++i) {
            ushort4 hq;
            float e;
            e = __builtin_amdgcn_exp2f(a2l * xn[i].x);
            hq.x = f2bf(fmaf(-2.0f, __builtin_amdgcn_rcpf(1.0f + e), 1.0f));
            e = __builtin_amdgcn_exp2f(a2l * xn[i].y);
            hq.y = f2bf(fmaf(-2.0f, __builtin_amdgcn_rcpf(1.0f + e), 1.0f));
            e = __builtin_amdgcn_exp2f(a2l * xn[i].z);
            hq.z = f2bf(fmaf(-2.0f, __builtin_amdgcn_rcpf(1.0f + e), 1.0f));
            e = __builtin_amdgcn_exp2f(a2l * xn[i].w);
            hq.w = f2bf(fmaf(-2.0f, __builtin_amdgcn_rcpf(1.0f + e), 1.0f));
            *reinterpret_cast<ushort4*>(&hA[buf][(i * 8 + srow) * PITCH + scol]) = hq;
        }
    };
    // MFMA + residual re-read (L2-hot) + fragment-order store
    auto compute = [&](int t) __attribute__((always_inline)) {
        const unsigned tb = blockBase + (unsigned)t * (ROWS * SIZE);
        const unsigned short* hb = &hA[t & 1][0];
#pragma unroll
        for (int mt = 0; mt < 2; ++mt) {
            const int r = mt * 16 + lrow;
            short8 hf[4];
#pragma unroll
            for (int kt = 0; kt < 4; ++kt)
                hf[kt] = *reinterpret_cast<const short8*>(
                    &hb[r * PITCH + kt * 32 + slot * 8]);
#pragma unroll
            for (int nt = 0; nt < 2; ++nt) {
                f32x4 a = {0.f, 0.f, 0.f, 0.f};
#pragma unroll
                for (int kt = 0; kt < 4; ++kt)
                    a = __builtin_amdgcn_mfma_f32_16x16x32_bf16(gf[nt][kt], hf[kt],
                                                                a, 0, 0, 0);
                const unsigned off =
                    tb + (unsigned)r * SIZE + (unsigned)(colb + nt * 16 + slot * 4);
                const float4 xa = *reinterpret_cast<const float4*>(&x[off]);
                float4 o;
                o.x = a[0] + c0v[nt].x + xa.x;
                o.y = a[1] + c0v[nt].y + xa.y;
                o.z = a[2] + c0v[nt].z + xa.z;
                o.w = a[3] + c0v[nt].w + xa.w;
                *reinterpret_cast<float4*>(&out[off]) = o;
            }
        }
    };

    // ---- prologue: tile 0 staged ----
    float4 xn[4];
    stage(0, xn);
    hwrite(0, xn);
    asm volatile("s_waitcnt lgkmcnt(0)\n\ts_barrier" ::: "memory");

    // ---- pipelined tile loop: 1 barrier/tile, vmcnt never drained ----
#pragma unroll
    for (int t = 0; t < TPB; ++t) {
        if (t + 1 < TPB) stage(t + 1, xn);  // async under compute(t)
        compute(t);
        if (t + 1 < TPB) {
            hwrite((t + 1) & 1, xn);        // waits only xn (compiler vmcnt)
            asm volatile("s_waitcnt lgkmcnt(0)\n\ts_barrier" ::: "memory");
        }
    }
}

extern "C" void kernel_launch(void* const* d_in, const int* in_sizes, int n_in,
                              void* d_out, int out_size, void* d_ws, size_t ws_size,
                              hipStream_t stream) {
    const float* x = (const float*)d_in[0];
    const float* alpha = (const float*)d_in[1];
    const float* dyt_w = (const float*)d_in[2];
    const float* dyt_b = (const float*)d_in[3];
    // d_in[4] = a_real, d_in[5] = a_imag, d_in[8] = ffn_bias: dead code in reference
    const float* b_real = (const float*)d_in[6];
    const float* b_imag = (const float*)d_in[7];
    float* out = (float*)d_out;

    unsigned short* Gt = (unsigned short*)d_ws;            // 32 KB bf16
    float* C0 = (float*)((char*)d_ws + SIZE * SIZE * 2);   // 512 B f32

    build_gt<<<1, 128, 0, stream>>>(b_real, b_imag, dyt_w, dyt_b, Gt, C0);

    const int rows = out_size / SIZE;          // 262144
    const int nblocks = rows / (ROWS * TPB);   // 1024
    fourier_main<<<nblocks, 256, 0, stream>>>(x, alpha, Gt, C0, out);
}

// Round 13
// 75.122 us; speedup vs baseline: 1.1470x; 1.0234x over previous
//
#include <hip/hip_runtime.h>

#define SIZE 128
#define ROWS 32     // rows per tile
#define TPB 8       // tiles per block: 262144/32/8 = 1024 blocks = 4/CU exact
#define PITCH 136   // hA row pitch in bf16; 272 B rows break pow2 bank stride

typedef short short8 __attribute__((ext_vector_type(8)));
typedef float f32x4 __attribute__((ext_vector_type(4)));

__device__ __forceinline__ unsigned short f2bf(float f) {
    unsigned int u = __float_as_uint(f);
    unsigned int r = u + 0x7FFFu + ((u >> 16) & 1u);
    return (unsigned short)(r >> 16);
}

// gr = Re(ifft(b)). DyT affine folded into the conv matrix:
//   Gt[c][k] = w[k] * gr[(c-k)&127]   (bf16, 32 KB)
//   C0[c]    = sum_k bias[k] * gr[(c-k)&127]   (f32, 512 B)
__global__ void build_gt(const float* __restrict__ br, const float* __restrict__ bi,
                         const float* __restrict__ w, const float* __restrict__ bias,
                         unsigned short* __restrict__ Gt, float* __restrict__ C0) {
    __shared__ float gr[SIZE];
    const int t = threadIdx.x;  // 0..127
    float acc = 0.0f;
    for (int j = 0; j < SIZE; ++j) {
        int p = (j * t) & 127;
        float a = (float)p * (1.0f / 64.0f);   // angle in units of pi
        acc += br[j] * cospif(a) - bi[j] * sinpif(a);
    }
    gr[t] = acc * (1.0f / 128.0f);
    __syncthreads();
    float c0 = 0.0f;
    for (int k = 0; k < SIZE; ++k) {
        const float g = gr[(t - k) & 127];
        c0 += bias[k] * g;
        Gt[t * SIZE + k] = f2bf(w[k] * g);
    }
    C0[t] = c0;
}

// out[r][c] = sum_k tanh(alpha*x[r][k]) * Gt[c][k] + C0[c] + x[r][c]
// Anti-burst-lockstep pipeline: loads for tile t+2 are ISSUED at the end of
// iteration t and WAITED at the end of iteration t+1 (a full compute +
// hwrite + barrier of headroom), so queue-inflated HBM latency doesn't
// stall waves and VMEM issue stays continuous. vmcnt is never drained
// (raw s_barrier + lgkmcnt only). Frag-footprint global I/O: x lives in
// registers from load to residual-add (4 loads + 4 stores per wave/tile,
// no re-read). Two xr register sets rotate (t%2); hA double-buffered.
__global__ __launch_bounds__(256, 4) void fourier_main(
    const float* __restrict__ x, const float* __restrict__ alpha_p,
    const unsigned short* __restrict__ Gt, const float* __restrict__ C0,
    float* __restrict__ out) {
    __shared__ unsigned short hA[2][ROWS * PITCH];  // 2 x 8.7 KB bf16 h tiles

    const int tid = threadIdx.x;
    const int lane = tid & 63;
    const int wv = tid >> 6;
    const int lrow = lane & 15;   // fragment row selector
    const int slot = lane >> 4;   // fragment k-chunk / col-group selector
    const int colb = wv * 32;     // this wave's column band

    // tanh(t) = 1 - 2/(1+2^(t*2*log2e)); fold 2*alpha*log2e into one constant
    const float a2l = 2.0f * 1.44269504f * alpha_p[0];

    // ---- G fragments (8 KB/wave, L2-resident) + C0 for this wave's cols ----
    short8 gf[2][4];
    float4 c0v[2];
#pragma unroll
    for (int nt = 0; nt < 2; ++nt) {
        const int c = colb + nt * 16 + lrow;
#pragma unroll
        for (int kt = 0; kt < 4; ++kt)
            gf[nt][kt] = *reinterpret_cast<const short8*>(
                &Gt[c * SIZE + kt * 32 + slot * 8]);
        c0v[nt] = *reinterpret_cast<const float4*>(&C0[colb + nt * 16 + slot * 4]);
    }

    const unsigned blockBase = (unsigned)blockIdx.x * (TPB * ROWS * SIZE);
    // this thread's static frag footprint within a tile: 4 float4 groups
    unsigned soff[2][2];
#pragma unroll
    for (int mt = 0; mt < 2; ++mt)
#pragma unroll
        for (int nt = 0; nt < 2; ++nt)
            soff[mt][nt] =
                (unsigned)((mt * 16 + lrow) * SIZE + colb + nt * 16 + slot * 4);

    // frag-order loads of tile t into a register set (issue-only; no wait here)
    auto stage = [&](int t, float4 (&xs)[2][2]) __attribute__((always_inline)) {
        const unsigned tb = blockBase + (unsigned)t * (ROWS * SIZE);
#pragma unroll
        for (int mt = 0; mt < 2; ++mt)
#pragma unroll
            for (int nt = 0; nt < 2; ++nt)
                xs[mt][nt] =
                    *reinterpret_cast<const float4*>(&x[tb + soff[mt][nt]]);
    };
    // tanh -> bf16 -> hA[buf] (first use of xs regs; compiler emits vmcnt(4))
    auto hwrite = [&](int buf, const float4 (&xs)[2][2])
        __attribute__((always_inline)) {
#pragma unroll
        for (int mt = 0; mt < 2; ++mt)
#pragma unroll
            for (int nt = 0; nt < 2; ++nt) {
                const float4 v = xs[mt][nt];
                ushort4 hq;
                float e;
                e = __builtin_amdgcn_exp2f(a2l * v.x);
                hq.x = f2bf(fmaf(-2.0f, __builtin_amdgcn_rcpf(1.0f + e), 1.0f));
                e = __builtin_amdgcn_exp2f(a2l * v.y);
                hq.y = f2bf(fmaf(-2.0f, __builtin_amdgcn_rcpf(1.0f + e), 1.0f));
                e = __builtin_amdgcn_exp2f(a2l * v.z);
                hq.z = f2bf(fmaf(-2.0f, __builtin_amdgcn_rcpf(1.0f + e), 1.0f));
                e = __builtin_amdgcn_exp2f(a2l * v.w);
                hq.w = f2bf(fmaf(-2.0f, __builtin_amdgcn_rcpf(1.0f + e), 1.0f));
                *reinterpret_cast<ushort4*>(
                    &hA[buf][(mt * 16 + lrow) * PITCH + colb + nt * 16 +
                             slot * 4]) = hq;
            }
    };
    // MFMA on hA[t&1]; residual from the same register set; frag-order store
    auto compute = [&](int t, const float4 (&xs)[2][2])
        __attribute__((always_inline)) {
        const unsigned tb = blockBase + (unsigned)t * (ROWS * SIZE);
        const unsigned short* hb = &hA[t & 1][0];
#pragma unroll
        for (int mt = 0; mt < 2; ++mt) {
            short8 hf[4];
#pragma unroll
            for (int kt = 0; kt < 4; ++kt)
                hf[kt] = *reinterpret_cast<const short8*>(
                    &hb[(mt * 16 + lrow) * PITCH + kt * 32 + slot * 8]);
#pragma unroll
            for (int nt = 0; nt < 2; ++nt) {
                f32x4 a = {0.f, 0.f, 0.f, 0.f};
#pragma unroll
                for (int kt = 0; kt < 4; ++kt)
                    a = __builtin_amdgcn_mfma_f32_16x16x32_bf16(gf[nt][kt], hf[kt],
                                                                a, 0, 0, 0);
                const float4 xa = xs[mt][nt];
                float4 o;
                o.x = a[0] + c0v[nt].x + xa.x;
                o.y = a[1] + c0v[nt].y + xa.y;
                o.z = a[2] + c0v[nt].z + xa.z;
                o.w = a[3] + c0v[nt].w + xa.w;
                *reinterpret_cast<float4*>(&out[tb + soff[mt][nt]]) = o;
            }
        }
    };

    float4 xr0[2][2], xr1[2][2];  // two rotating register sets (tile t%2)

    // ---- prologue: tiles 0 and 1 in flight; h(0) staged ----
    stage(0, xr0);
    stage(1, xr1);
    hwrite(0, xr0);  // waits vmcnt(4): tile-0 loads done, tile-1 still in flight
    asm volatile("s_waitcnt lgkmcnt(0)\n\ts_barrier" ::: "memory");

    // ---- pipelined loop: issue(t+2) ... wait(t+1) one full iteration later ----
#pragma unroll
    for (int t = 0; t < TPB; ++t) {
        float4(&xc)[2][2] = (t & 1) ? xr1 : xr0;    // tile t (loaded 2 iters ago)
        float4(&xn)[2][2] = (t & 1) ? xr0 : xr1;    // tile t+1 (one iter ago)
        compute(t, xc);                              // consumes xc; no vm wait
        if (t + 2 < TPB) stage(t + 2, xc);           // reuse xc's regs, issue-only
        if (t + 1 < TPB) {
            hwrite((t + 1) & 1, xn);  // vmcnt leaves tile-(t+2) loads in flight
            asm volatile("s_waitcnt lgkmcnt(0)\n\ts_barrier" ::: "memory");
        }
    }
}

extern "C" void kernel_launch(void* const* d_in, const int* in_sizes, int n_in,
                              void* d_out, int out_size, void* d_ws, size_t ws_size,
                              hipStream_t stream) {
    const float* x = (const float*)d_in[0];
    const float* alpha = (const float*)d_in[1];
    const float* dyt_w = (const float*)d_in[2];
    const float* dyt_b = (const float*)d_in[3];
    // d_in[4] = a_real, d_in[5] = a_imag, d_in[8] = ffn_bias: dead code in reference
    const float* b_real = (const float*)d_in[6];
    const float* b_imag = (const float*)d_in[7];
    float* out = (float*)d_out;

    unsigned short* Gt = (unsigned short*)d_ws;            // 32 KB bf16
    float* C0 = (float*)((char*)d_ws + SIZE * SIZE * 2);   // 512 B f32

    build_gt<<<1, 128, 0, stream>>>(b_real, b_imag, dyt_w, dyt_b, Gt, C0);

    const int rows = out_size / SIZE;          // 262144
    const int nblocks = rows / (ROWS * TPB);   // 1024
    fourier_main<<<nblocks, 256, 0, stream>>>(x, alpha, Gt, C0, out);
}